// Round 9
// baseline (126.002 us; speedup 1.0000x reference)
//
#include <hip/hip_runtime.h>
#include <hip/hip_bf16.h>

// out[b,d,h,t,s] = sum_f qk[b,d,h,t,f] * lut[bucket(pd[b,t,s])][h][f]
// B=4 D=1024 H=12 T=32 S=32 F=64. All global buffers fp32 (pd int32).
// R8 post-mortem: R6/R7/R8 = 130/125/124us, all ~78% of copy ceiling; all
// share 8k-32k concurrent short-burst DRAM streams + per-step full-CU
// barrier drains. R9: 256 blocks (1/CU), block = (b, d-chunk) x ALL 12 h ->
// 16 sequential 96KB read streams/block (4096 chip-wide, 4x fewer), fully
// double-buffered LDS (Qs+Os+Rl = 139KB), ONE barrier per step, 24 steps.
constexpr int Bc = 4, Dc = 1024, Hc = 12, Tc = 32, Sc = 32, Fc = 64;
constexpr int QP = 1032;             // Qs bf16 pitch (516 dw == 4 mod 32)
constexpr int OP = 516;              // Os f32 pitch  (516 dw == 4 mod 32)
constexpr int STEPS = 24;            // (h, t-half)

typedef __bf16 bf16x8 __attribute__((ext_vector_type(8)));
typedef __bf16 bf16x4 __attribute__((ext_vector_type(4)));
typedef float  f32x4  __attribute__((ext_vector_type(4)));

__global__ __launch_bounds__(1024, 4) void rpe_stream(
    const float* __restrict__ qk,
    const int*   __restrict__ pdist,
    const float* __restrict__ lut,
    float*       __restrict__ out)
{
    __shared__ __align__(16) __bf16 Qs[2][16][QP];   // 66 KB dbuf q slabs
    __shared__ __align__(16) float  Os[2][16][OP];   // 66 KB dbuf out slabs
    __shared__ __align__(16) __bf16 Rl[2][32][72];   // 9.2 KB dbuf bucket tbl
    __shared__ unsigned char idxl[Tc][Sc];           // 1 KB

    const int bid = blockIdx.x;
    const int dc  = bid & 63;
    const int b   = bid >> 6;
    const int d0  = dc * 16;

    const int tid = threadIdx.x;
    const int w   = tid >> 6;        // wave 0..15: staging d-row / compute t-loc
    const int l   = tid & 63;
    const int r16 = l & 15;          // MFMA n -> d; A-row m -> s
    const int grp = l >> 4;          // k-group (0..3)
    const int rbu = tid >> 4;        // bucket (valid for tid<512)
    const int rf0 = (tid & 15) * 4;  // f offset for Rl staging

    // wave w owns d-row d0+w for staging and output streaming.
    const float* qsrc  = qk  + (size_t)((b * Dc + d0 + w) * Hc) * Tc * Fc + l * 4;
    float*       obase = out + (size_t)((b * Dc + d0 + w) * Hc) * Tc * Sc;

    // ---- prologue: idx table, Rl[h=0], Qs[step 0] ----
    if (tid < 256) {
        const int t  = tid >> 3;
        const int s0 = (tid & 7) * 4;
        const int4 p = *reinterpret_cast<const int4*>(pdist + (b * Tc + t) * Sc + s0);
        uchar4 u; int v;
        v = p.x; v = v < -15 ? -15 : (v > 16 ? 16 : v); u.x = (unsigned char)(v < 0 ? v + 32 : v);
        v = p.y; v = v < -15 ? -15 : (v > 16 ? 16 : v); u.y = (unsigned char)(v < 0 ? v + 32 : v);
        v = p.z; v = v < -15 ? -15 : (v > 16 ? 16 : v); u.z = (unsigned char)(v < 0 ? v + 32 : v);
        v = p.w; v = v < -15 ? -15 : (v > 16 ? 16 : v); u.w = (unsigned char)(v < 0 ? v + 32 : v);
        *reinterpret_cast<uchar4*>(&idxl[t][s0]) = u;
    }
    if (tid < 512) {
        f32x4 rg = *reinterpret_cast<const f32x4*>(lut + (rbu * Hc) * Fc + rf0);
        bf16x4 w4;
        #pragma unroll
        for (int k = 0; k < 4; ++k) w4[k] = (__bf16)rg[k];
        *reinterpret_cast<bf16x4*>(&Rl[0][rbu][rf0]) = w4;
    }
    #pragma unroll
    for (int k = 0; k < 4; ++k) {
        f32x4 v = *reinterpret_cast<const f32x4*>(qsrc + k * 256);
        bf16x4 q4;
        #pragma unroll
        for (int j = 0; j < 4; ++j) q4[j] = (__bf16)v[j];
        *reinterpret_cast<bf16x4*>(&Qs[0][w][k * 256 + l * 4]) = q4;
    }
    __syncthreads();

    #pragma unroll 2
    for (int s = 0; s < STEPS; ++s) {
        const int cur = s & 1;
        const int h   = s >> 1;
        const int th  = s & 1;

        // (A) issue next step's global loads (consumed in D, after B+C)
        f32x4 g0, g1, g2, g3, rg;
        if (s < STEPS - 1) {
            const float* qp = qsrc + ((s + 1) >> 1) * 2048 + ((s + 1) & 1) * 1024;
            g0 = *reinterpret_cast<const f32x4*>(qp);
            g1 = *reinterpret_cast<const f32x4*>(qp + 256);
            g2 = *reinterpret_cast<const f32x4*>(qp + 512);
            g3 = *reinterpret_cast<const f32x4*>(qp + 768);
            if ((s & 1) && tid < 512)
                rg = *reinterpret_cast<const f32x4*>(
                    lut + (rbu * Hc + h + 1) * Fc + rf0);
        }

        // (B) MFMA from Qs[cur]; deposit into Os[cur]. wave w = t-loc.
        {
            const int tg = th * 16 + w;
            const int i0 = idxl[tg][r16];
            const int i1 = idxl[tg][16 + r16];
            const int hp = h & 1;
            bf16x8 a00 = *reinterpret_cast<const bf16x8*>(&Rl[hp][i0][grp * 8]);
            bf16x8 a01 = *reinterpret_cast<const bf16x8*>(&Rl[hp][i0][32 + grp * 8]);
            bf16x8 a10 = *reinterpret_cast<const bf16x8*>(&Rl[hp][i1][grp * 8]);
            bf16x8 a11 = *reinterpret_cast<const bf16x8*>(&Rl[hp][i1][32 + grp * 8]);
            bf16x8 bf0 = *reinterpret_cast<const bf16x8*>(&Qs[cur][r16][w * 64 + grp * 8]);
            bf16x8 bf1 = *reinterpret_cast<const bf16x8*>(&Qs[cur][r16][w * 64 + 32 + grp * 8]);

            f32x4 acc0 = {0.f, 0.f, 0.f, 0.f};
            f32x4 acc1 = {0.f, 0.f, 0.f, 0.f};
            acc0 = __builtin_amdgcn_mfma_f32_16x16x32_bf16(a00, bf0, acc0, 0, 0, 0);
            acc0 = __builtin_amdgcn_mfma_f32_16x16x32_bf16(a01, bf1, acc0, 0, 0, 0);
            acc1 = __builtin_amdgcn_mfma_f32_16x16x32_bf16(a10, bf0, acc1, 0, 0, 0);
            acc1 = __builtin_amdgcn_mfma_f32_16x16x32_bf16(a11, bf1, acc1, 0, 0, 0);

            *reinterpret_cast<f32x4*>(&Os[cur][r16][w * 32 + grp * 4])      = acc0;
            *reinterpret_cast<f32x4*>(&Os[cur][r16][w * 32 + 16 + grp * 4]) = acc1;
        }

        // (C) stream previous step's Os slab to global (wave w = d-row).
        if (s > 0) {
            const int sp = s - 1;
            float* op = obase + (sp >> 1) * 1024 + (sp & 1) * 512 + l * 4;
            f32x4 v0 = *reinterpret_cast<const f32x4*>(&Os[cur ^ 1][w][l * 4]);
            f32x4 v1 = *reinterpret_cast<const f32x4*>(&Os[cur ^ 1][w][256 + l * 4]);
            *reinterpret_cast<f32x4*>(op)       = v0;
            *reinterpret_cast<f32x4*>(op + 256) = v1;
        }

        // (D) convert + deposit next slab; stage Rl for h+1 on odd steps.
        if (s < STEPS - 1) {
            bf16x4 q4;
            #pragma unroll
            for (int j = 0; j < 4; ++j) q4[j] = (__bf16)g0[j];
            *reinterpret_cast<bf16x4*>(&Qs[cur ^ 1][w][l * 4]) = q4;
            #pragma unroll
            for (int j = 0; j < 4; ++j) q4[j] = (__bf16)g1[j];
            *reinterpret_cast<bf16x4*>(&Qs[cur ^ 1][w][256 + l * 4]) = q4;
            #pragma unroll
            for (int j = 0; j < 4; ++j) q4[j] = (__bf16)g2[j];
            *reinterpret_cast<bf16x4*>(&Qs[cur ^ 1][w][512 + l * 4]) = q4;
            #pragma unroll
            for (int j = 0; j < 4; ++j) q4[j] = (__bf16)g3[j];
            *reinterpret_cast<bf16x4*>(&Qs[cur ^ 1][w][768 + l * 4]) = q4;

            if ((s & 1) && tid < 512) {
                bf16x4 w4;
                #pragma unroll
                for (int k = 0; k < 4; ++k) w4[k] = (__bf16)rg[k];
                *reinterpret_cast<bf16x4*>(&Rl[(h + 1) & 1][rbu][rf0]) = w4;
            }
        }
        __syncthreads();
    }

    // epilogue: stream the final step's Os (s=23: h=11, th=1, buf 1)
    {
        float* op = obase + 11 * 1024 + 512 + l * 4;
        f32x4 v0 = *reinterpret_cast<const f32x4*>(&Os[1][w][l * 4]);
        f32x4 v1 = *reinterpret_cast<const f32x4*>(&Os[1][w][256 + l * 4]);
        *reinterpret_cast<f32x4*>(op)       = v0;
        *reinterpret_cast<f32x4*>(op + 256) = v1;
    }
}

extern "C" void kernel_launch(void* const* d_in, const int* in_sizes, int n_in,
                              void* d_out, int out_size, void* d_ws, size_t ws_size,
                              hipStream_t stream) {
    const float* qk    = (const float*)d_in[0];
    const int*   pdist = (const int*)d_in[1];
    const float* lut   = (const float*)d_in[2];
    float*       out   = (float*)d_out;

    const int grid = Bc * 64;        // (b, d-chunk) = 256 blocks, 1 per CU
    rpe_stream<<<grid, 1024, 0, stream>>>(qk, pdist, lut, out);
}